// Round 1
// baseline (434.734 us; speedup 1.0000x reference)
//
#include <hip/hip_runtime.h>
#include <hip/hip_bf16.h>
#include <cstdint>
#include <cstddef>

#define T_SEQ 2048
#define NBATCH 2
#define DIMD 512
#define NH 8
#define NS 16
#define HD 64
#define NBH 16          // NBATCH*NH
#define NROWS 4096      // NBATCH*T_SEQ

// workspace layout (float offsets)
static const size_t OFF_QKV  = 0;                                  // 4096*1536
static const size_t OFF_QA   = OFF_QKV  + (size_t)NROWS * 1536;    // qa[bh][i][s]  (q_w * amp/temp)
static const size_t OFF_KW   = OFF_QA   + (size_t)NBH * T_SEQ * NS;// kw[bh][j][s]  (k_w)
static const size_t OFF_SINV = OFF_KW   + (size_t)NBH * T_SEQ * NS;// 1/colsum per (bh, j)
static const size_t OFF_AOUT = OFF_SINV + (size_t)NBH * T_SEQ;     // attn output (B,T,D) pre-Wout
static const size_t OFF_CADJ = OFF_AOUT + (size_t)NROWS * DIMD;    // adjusted centers
static const size_t OFF_IVAR = OFF_CADJ + (size_t)NH * NS * HD;
static const size_t OFF_AMPT = OFF_IVAR + (size_t)NH * NS;

// ---------------------------------------------------------------- K0: params
__global__ __launch_bounds__(256) void k0_params(
    const float* __restrict__ centers, const float* __restrict__ deltas,
    const float* __restrict__ lsc, const float* __restrict__ lam,
    const float* __restrict__ ms, const float* __restrict__ tp,
    float* __restrict__ cadj, float* __restrict__ ivar, float* __restrict__ ampt) {
  int tid = threadIdx.x;
  float bscale = 0.2f / (1.0f + expf(-ms[0]));           // sigmoid * 0.2
  float tclip = fminf(fmaxf(tp[0], 0.1f), 10.0f);
  if (tid < NH * NS) {
    float sc = fminf(fmaxf(expf(lsc[tid]), 0.01f), 2.0f);
    ivar[tid] = 1.0f / (sc * sc + 1e-8f);
    float am = fminf(fmaxf(expf(lam[tid]), 1e-6f), 10.0f);
    am = (am > 0.02f) ? am : 0.0f;                       // pruning
    ampt[tid] = am / tclip;                              // fold amp and 1/temp into qa
  }
  for (int e = tid; e < NH * NS * HD; e += 256)
    cadj[e] = centers[e] + deltas[e] * bscale;
}

// ------------------------------------------------- GEMM: C[M,N] = A[M,K]*B[N,K]^T
// BM=BN=64, BK=32, 256 threads, 4x4 microtile, fp32 vector ALU.
__global__ __launch_bounds__(256) void gemm_tn(
    const float* __restrict__ A, const float* __restrict__ B, float* __restrict__ C,
    int M, int N, int K) {
  __shared__ float a_s[64][36];   // [row][k], pad 36 keeps float4 rows 16B-aligned
  __shared__ float b_s[64][36];
  int tid = threadIdx.x;
  int tx = tid & 15, ty = tid >> 4;
  int m0 = blockIdx.y << 6, n0 = blockIdx.x << 6;
  float acc[4][4] = {};
  for (int k0 = 0; k0 < K; k0 += 32) {
    __syncthreads();
#pragma unroll
    for (int t = 0; t < 2; ++t) {
      int f = tid + (t << 8);          // 0..511 float4 slots
      int r = f >> 3, kq = f & 7;
      *(float4*)&a_s[r][kq << 2] = *(const float4*)&A[(size_t)(m0 + r) * K + k0 + (kq << 2)];
      *(float4*)&b_s[r][kq << 2] = *(const float4*)&B[(size_t)(n0 + r) * K + k0 + (kq << 2)];
    }
    __syncthreads();
#pragma unroll
    for (int kk = 0; kk < 8; ++kk) {
      float a4[4][4], b4[4][4];
#pragma unroll
      for (int r = 0; r < 4; ++r) {
        float4 v = *(const float4*)&a_s[ty + (r << 4)][kk << 2];
        a4[r][0] = v.x; a4[r][1] = v.y; a4[r][2] = v.z; a4[r][3] = v.w;
      }
#pragma unroll
      for (int c = 0; c < 4; ++c) {
        float4 v = *(const float4*)&b_s[tx + (c << 4)][kk << 2];
        b4[c][0] = v.x; b4[c][1] = v.y; b4[c][2] = v.z; b4[c][3] = v.w;
      }
#pragma unroll
      for (int kj = 0; kj < 4; ++kj)
#pragma unroll
        for (int r = 0; r < 4; ++r)
#pragma unroll
          for (int c = 0; c < 4; ++c)
            acc[r][c] = fmaf(a4[r][kj], b4[c][kj], acc[r][c]);
    }
  }
#pragma unroll
  for (int r = 0; r < 4; ++r)
#pragma unroll
    for (int c = 0; c < 4; ++c)
      C[(size_t)(m0 + ty + (r << 4)) * N + n0 + tx + (c << 4)] = acc[r][c];
}

// ------------------------------------------- K2: splat features qa, kw from q,k
__global__ __launch_bounds__(256) void k2_feat(
    const float* __restrict__ qkv, const float* __restrict__ cadj,
    const float* __restrict__ ivar, const float* __restrict__ ampt,
    float* __restrict__ qa, float* __restrict__ kw) {
  int bh = blockIdx.y; int b = bh >> 3, h = bh & 7;
  int i0 = blockIdx.x << 5;   // 32 rows per block
  int tid = threadIdx.x;
  __shared__ float q_s[32][68], k_s[32][68], c_s[16][68];  // pad 68 vs bank conflicts
#pragma unroll
  for (int t = 0; t < 4; ++t) {
    int f = tid + (t << 8);               // 0..1023 float4 slots (q then k)
    int mat = f >> 9, g = f & 511;
    int r = g >> 4, d4 = g & 15;
    float4 v = *(const float4*)&qkv[(size_t)(b * T_SEQ + i0 + r) * 1536 + mat * 512 + h * 64 + (d4 << 2)];
    float* dst = mat ? &k_s[r][d4 << 2] : &q_s[r][d4 << 2];
    *(float4*)dst = v;
  }
  {
    int r = tid >> 4, d4 = tid & 15;
    *(float4*)&c_s[r][d4 << 2] = *(const float4*)&cadj[(h * 16 + r) * 64 + (d4 << 2)];
  }
  __syncthreads();
#pragma unroll
  for (int t = 0; t < 4; ++t) {
    int task = (t << 8) + tid;            // 0..1023 = 32 rows x 16 splats x {q,k}
    int is_k = task >> 9, g = task & 511;
    int r = g >> 4, s = g & 15;
    const float* row = is_k ? k_s[r] : q_s[r];
    float acc = 0.0f;
#pragma unroll 8
    for (int d = 0; d < 64; ++d) {
      float df = row[d] - c_s[s][d];
      acc = fmaf(df, df, acc);
    }
    float val = __expf(-0.5f * acc * ivar[h * 16 + s]);
    if (!is_k) val *= ampt[h * 16 + s];
    float* dst = is_k ? kw : qa;
    dst[((size_t)bh * T_SEQ + i0 + r) * 16 + s] = val;
  }
}

// --------------------------- K3: column sums S[j] = sum_i exp(l[i,j]) -> 1/S
__global__ __launch_bounds__(256) void k3_colsum(
    const float* __restrict__ qa, const float* __restrict__ kw, float* __restrict__ sinv) {
  int bh = blockIdx.y;
  int j0 = blockIdx.x << 6;               // 64 columns per block
  int tid = threadIdx.x;
  int jl = tid & 63;
  int stripe = __builtin_amdgcn_readfirstlane(tid >> 6);   // wave-uniform -> scalar loads of qa
  __shared__ float red[4][64];
  float kwr[16];
  {
    const float* kp = &kw[((size_t)bh * T_SEQ + j0 + jl) * 16];
#pragma unroll
    for (int s4 = 0; s4 < 4; ++s4) {
      float4 v = *(const float4*)(kp + (s4 << 2));
      kwr[s4 * 4 + 0] = v.x; kwr[s4 * 4 + 1] = v.y; kwr[s4 * 4 + 2] = v.z; kwr[s4 * 4 + 3] = v.w;
    }
  }
  float ssum = 0.0f;
  const float* qbase = &qa[((size_t)bh * T_SEQ + stripe * 512) * 16];
  for (int ii = 0; ii < 512; ++ii) {
    float l = 0.0f;
#pragma unroll
    for (int s = 0; s < 16; ++s) l = fmaf(qbase[ii * 16 + s], kwr[s], l);
    ssum += __expf(l);
  }
  red[stripe][jl] = ssum;
  __syncthreads();
  if (tid < 64) {
    float tot = red[0][tid] + red[1][tid] + red[2][tid] + red[3][tid];
    sinv[(size_t)bh * T_SEQ + j0 + tid] = 1.0f / tot;
  }
}

// ------------- K4: out[i,d] = sum_j exp(l[i,j]) * v[j,d] * sinv[j]  (per b,h)
__global__ __launch_bounds__(256) void k4_attnout(
    const float* __restrict__ qa, const float* __restrict__ kw,
    const float* __restrict__ sinv, const float* __restrict__ qkv,
    float* __restrict__ aout) {
  int bh = blockIdx.y; int b = bh >> 3, h = bh & 7;
  int i0 = blockIdx.x << 6;               // 64-row i tile
  int tid = threadIdx.x;
  __shared__ float vs_s[32][64];
  __shared__ float p_s[64][36];           // pad 36: aligned float4 rows
  int ip = tid & 63;
  int jgrp = __builtin_amdgcn_readfirstlane(tid >> 6);  // wave-uniform -> scalar kw loads
  float qar[16];
  {
    const float* qp = &qa[((size_t)bh * T_SEQ + i0 + ip) * 16];
#pragma unroll
    for (int s4 = 0; s4 < 4; ++s4) {
      float4 v = *(const float4*)(qp + (s4 << 2));
      qar[s4 * 4 + 0] = v.x; qar[s4 * 4 + 1] = v.y; qar[s4 * 4 + 2] = v.z; qar[s4 * 4 + 3] = v.w;
    }
  }
  int tx = tid & 15, ty = tid >> 4;
  float acc[4][4] = {};
  const float* vbase = qkv + (size_t)b * T_SEQ * 1536 + 1024 + h * 64;
  const float* svbase = sinv + (size_t)bh * T_SEQ;
  for (int jc = 0; jc < 64; ++jc) {
    int j0 = jc << 5;                     // 32 j per chunk
    __syncthreads();                      // prev MAC done before restaging vs_s
#pragma unroll
    for (int t = 0; t < 2; ++t) {
      int f = tid + (t << 8);
      int jr = f >> 4, d4 = f & 15;
      float sv = svbase[j0 + jr];
      float4 v = *(const float4*)&vbase[(size_t)(j0 + jr) * 1536 + (d4 << 2)];
      v.x *= sv; v.y *= sv; v.z *= sv; v.w *= sv;
      *(float4*)&vs_s[jr][d4 << 2] = v;
    }
    __syncthreads();
    // p phase: each thread computes 8 exp(l) values for its row ip
#pragma unroll
    for (int m = 0; m < 8; ++m) {
      int jj = (jgrp << 3) + m;
      const float* kp = &kw[((size_t)bh * T_SEQ + j0 + jj) * 16];
      float l = 0.0f;
#pragma unroll
      for (int s4 = 0; s4 < 4; ++s4) {
        float4 kv = *(const float4*)(kp + (s4 << 2));
        l = fmaf(qar[s4 * 4 + 0], kv.x, l);
        l = fmaf(qar[s4 * 4 + 1], kv.y, l);
        l = fmaf(qar[s4 * 4 + 2], kv.z, l);
        l = fmaf(qar[s4 * 4 + 3], kv.w, l);
      }
      p_s[ip][jj] = __expf(l);
    }
    __syncthreads();
    // MAC phase: acc[r][c] over 32 j
#pragma unroll
    for (int jj4 = 0; jj4 < 8; ++jj4) {
      float pa[4][4];
#pragma unroll
      for (int r = 0; r < 4; ++r) {
        float4 v = *(const float4*)&p_s[ty + (r << 4)][jj4 << 2];
        pa[r][0] = v.x; pa[r][1] = v.y; pa[r][2] = v.z; pa[r][3] = v.w;
      }
#pragma unroll
      for (int kj = 0; kj < 4; ++kj) {
        float4 vb = *(const float4*)&vs_s[(jj4 << 2) + kj][tx << 2];
#pragma unroll
        for (int r = 0; r < 4; ++r) {
          acc[r][0] = fmaf(pa[r][kj], vb.x, acc[r][0]);
          acc[r][1] = fmaf(pa[r][kj], vb.y, acc[r][1]);
          acc[r][2] = fmaf(pa[r][kj], vb.z, acc[r][2]);
          acc[r][3] = fmaf(pa[r][kj], vb.w, acc[r][3]);
        }
      }
    }
  }
#pragma unroll
  for (int r = 0; r < 4; ++r) {
    float4 o;
    o.x = acc[r][0]; o.y = acc[r][1]; o.z = acc[r][2]; o.w = acc[r][3];
    *(float4*)&aout[(size_t)(b * T_SEQ + i0 + ty + (r << 4)) * DIMD + h * 64 + (tx << 2)] = o;
  }
}

// ----------------------------------------------------------------------------
extern "C" void kernel_launch(void* const* d_in, const int* in_sizes, int n_in,
                              void* d_out, int out_size, void* d_ws, size_t ws_size,
                              hipStream_t stream) {
  const float* x    = (const float*)d_in[0];
  const float* Wqkv = (const float*)d_in[1];
  const float* Wout = (const float*)d_in[2];
  const float* ctr  = (const float*)d_in[3];
  const float* dlt  = (const float*)d_in[4];
  const float* lsc  = (const float*)d_in[5];
  const float* lam  = (const float*)d_in[6];
  const float* ms   = (const float*)d_in[7];
  const float* tp   = (const float*)d_in[8];
  float* ws   = (float*)d_ws;
  float* qkv  = ws + OFF_QKV;
  float* qa   = ws + OFF_QA;
  float* kwp  = ws + OFF_KW;
  float* sinv = ws + OFF_SINV;
  float* aout = ws + OFF_AOUT;
  float* cadj = ws + OFF_CADJ;
  float* ivar = ws + OFF_IVAR;
  float* ampt = ws + OFF_AMPT;
  float* out  = (float*)d_out;

  hipLaunchKernelGGL(k0_params, dim3(1), dim3(256), 0, stream,
                     ctr, dlt, lsc, lam, ms, tp, cadj, ivar, ampt);
  hipLaunchKernelGGL(gemm_tn, dim3(1536 / 64, 4096 / 64), dim3(256), 0, stream,
                     x, Wqkv, qkv, 4096, 1536, 512);
  hipLaunchKernelGGL(k2_feat, dim3(64, 16), dim3(256), 0, stream,
                     qkv, cadj, ivar, ampt, qa, kwp);
  hipLaunchKernelGGL(k3_colsum, dim3(32, 16), dim3(256), 0, stream,
                     qa, kwp, sinv);
  hipLaunchKernelGGL(k4_attnout, dim3(32, 16), dim3(256), 0, stream,
                     qa, kwp, sinv, qkv, aout);
  hipLaunchKernelGGL(gemm_tn, dim3(512 / 64, 4096 / 64), dim3(256), 0, stream,
                     aout, Wout, out, 4096, 512, 512);
}

// Round 2
// 170.686 us; speedup vs baseline: 2.5470x; 2.5470x over previous
//
#include <hip/hip_runtime.h>
#include <hip/hip_bf16.h>
#include <cstdint>
#include <cstddef>

#define T_SEQ 2048
#define NBATCH 2
#define DIMD 512
#define NH 8
#define NS 16
#define HD 64
#define NBH 16

using s16x8 = __attribute__((ext_vector_type(8))) short;
using f32x4 = __attribute__((ext_vector_type(4))) float;

static __device__ inline unsigned short f2bf(float f) {
  __hip_bfloat16 h = __float2bfloat16(f);
  return reinterpret_cast<unsigned short&>(h);
}
static __device__ inline float bf2f(unsigned short u) {
  union { unsigned int i; float f; } c; c.i = ((unsigned)u) << 16; return c.f;
}

// ---- workspace layout (float offsets, all 16-aligned) ----
static const size_t OFF_QKV  = 0;                       // 4096x1536 f32
static const size_t OFF_XH   = OFF_QKV  + 6291456;      // 4096x512 bf16 (as 1048576 f)  [aliased: aout_h]
static const size_t OFF_XL   = OFF_XH   + 1048576;      //                               [aliased: aout_l]
static const size_t OFF_WQH  = OFF_XL   + 1048576;      // 1536x512 bf16
static const size_t OFF_WQL  = OFF_WQH  + 393216;
static const size_t OFF_WOH  = OFF_WQL  + 393216;       // 512x512 bf16
static const size_t OFF_WOL  = OFF_WOH  + 131072;
static const size_t OFF_QABF = OFF_WOL  + 131072;       // 16x2048x32 bf16 (padded K)
static const size_t OFF_KWBF = OFF_QABF + 524288;
static const size_t OFF_SINV = OFF_KWBF + 524288;       // 16x2048 f32
static const size_t OFF_VPART= OFF_SINV + 32768;        // 8x16x64 f32
static const size_t OFF_CADJ = OFF_VPART+ 8192;
static const size_t OFF_IVAR = OFF_CADJ + 8192;
static const size_t OFF_AMPT = OFF_IVAR + 128;

// ---------------------------------------------------------------- K0: params
__global__ __launch_bounds__(256) void k0_params(
    const float* __restrict__ centers, const float* __restrict__ deltas,
    const float* __restrict__ lsc, const float* __restrict__ lam,
    const float* __restrict__ ms, const float* __restrict__ tp,
    float* __restrict__ cadj, float* __restrict__ ivar, float* __restrict__ ampt) {
  int tid = threadIdx.x;
  float bscale = 0.2f / (1.0f + expf(-ms[0]));
  float tclip = fminf(fmaxf(tp[0], 0.1f), 10.0f);
  if (tid < NH * NS) {
    float sc = fminf(fmaxf(expf(lsc[tid]), 0.01f), 2.0f);
    ivar[tid] = 1.0f / (sc * sc + 1e-8f);
    float am = fminf(fmaxf(expf(lam[tid]), 1e-6f), 10.0f);
    am = (am > 0.02f) ? am : 0.0f;
    ampt[tid] = am / tclip;
  }
  for (int e = tid; e < NH * NS * HD; e += 256)
    cadj[e] = centers[e] + deltas[e] * bscale;
}

// ------------------------------------------------ K1: split fp32 -> bf16 hi/lo
__global__ __launch_bounds__(256) void k1_split(
    const float* __restrict__ src, unsigned short* __restrict__ dh,
    unsigned short* __restrict__ dl, int n4) {
  int i4 = blockIdx.x * 256 + threadIdx.x;
  if (i4 >= n4) return;
  float4 v = *(const float4*)&src[(size_t)i4 * 4];
  ushort4 hh, ll;
  hh.x = f2bf(v.x); ll.x = f2bf(v.x - bf2f(hh.x));
  hh.y = f2bf(v.y); ll.y = f2bf(v.y - bf2f(hh.y));
  hh.z = f2bf(v.z); ll.z = f2bf(v.z - bf2f(hh.z));
  hh.w = f2bf(v.w); ll.w = f2bf(v.w - bf2f(hh.w));
  *(ushort4*)&dh[(size_t)i4 * 4] = hh;
  *(ushort4*)&dl[(size_t)i4 * 4] = ll;
}

// -------------------- split-bf16 MFMA GEMM: C[M,N] = A[M,K] * B[N,K]^T (fp32 out)
template<int BM, int BN>
__global__ __launch_bounds__(256) void gemm_split(
    const unsigned short* __restrict__ Ah, const unsigned short* __restrict__ Al,
    const unsigned short* __restrict__ Bh, const unsigned short* __restrict__ Bl,
    float* __restrict__ C, int M, int N, int K) {
  constexpr int WM = BM / 2, WN = BN / 2;
  constexpr int MF = WM / 16, NF = WN / 16;
  __shared__ __align__(16) unsigned short ash[BM * 40], asl[BM * 40];
  __shared__ __align__(16) unsigned short bsh[BN * 40], bsl[BN * 40];
  int tid = threadIdx.x;
  int w = tid >> 6, l = tid & 63, lm = l & 15, lq = l >> 4;
  int wm = w >> 1, wn = w & 1;
  int m0 = blockIdx.y * BM, n0 = blockIdx.x * BN;
  f32x4 acc[MF][NF];
#pragma unroll
  for (int mi = 0; mi < MF; ++mi)
#pragma unroll
    for (int ni = 0; ni < NF; ++ni) acc[mi][ni] = (f32x4){0.f, 0.f, 0.f, 0.f};

  for (int k0 = 0; k0 < K; k0 += 32) {
    __syncthreads();
#pragma unroll
    for (int c = tid; c < BM * 4; c += 256) {
      int r = c >> 2, s = c & 3;
      size_t ga = (size_t)(m0 + r) * K + k0 + s * 8;
      *(float4*)&ash[r * 40 + s * 8] = *(const float4*)&Ah[ga];
      *(float4*)&asl[r * 40 + s * 8] = *(const float4*)&Al[ga];
    }
#pragma unroll
    for (int c = tid; c < BN * 4; c += 256) {
      int r = c >> 2, s = c & 3;
      size_t ga = (size_t)(n0 + r) * K + k0 + s * 8;
      *(float4*)&bsh[r * 40 + s * 8] = *(const float4*)&Bh[ga];
      *(float4*)&bsl[r * 40 + s * 8] = *(const float4*)&Bl[ga];
    }
    __syncthreads();
    s16x8 fah[MF], fal[MF], fbh[NF], fbl[NF];
#pragma unroll
    for (int mi = 0; mi < MF; ++mi) {
      int ro = (wm * WM + mi * 16 + lm) * 40 + lq * 8;
      fah[mi] = *(const s16x8*)&ash[ro];
      fal[mi] = *(const s16x8*)&asl[ro];
    }
#pragma unroll
    for (int ni = 0; ni < NF; ++ni) {
      int ro = (wn * WN + ni * 16 + lm) * 40 + lq * 8;
      fbh[ni] = *(const s16x8*)&bsh[ro];
      fbl[ni] = *(const s16x8*)&bsl[ro];
    }
#pragma unroll
    for (int mi = 0; mi < MF; ++mi)
#pragma unroll
      for (int ni = 0; ni < NF; ++ni) {
        acc[mi][ni] = __builtin_amdgcn_mfma_f32_16x16x32_bf16(fah[mi], fbh[ni], acc[mi][ni], 0, 0, 0);
        acc[mi][ni] = __builtin_amdgcn_mfma_f32_16x16x32_bf16(fah[mi], fbl[ni], acc[mi][ni], 0, 0, 0);
        acc[mi][ni] = __builtin_amdgcn_mfma_f32_16x16x32_bf16(fal[mi], fbh[ni], acc[mi][ni], 0, 0, 0);
      }
  }
#pragma unroll
  for (int mi = 0; mi < MF; ++mi)
#pragma unroll
    for (int ni = 0; ni < NF; ++ni)
#pragma unroll
      for (int r = 0; r < 4; ++r) {
        int row = m0 + wm * WM + mi * 16 + lq * 4 + r;
        int col = n0 + wn * WN + ni * 16 + lm;
        C[(size_t)row * N + col] = acc[mi][ni][r];
      }
}

// ------------------------------------------- K2: splat features -> bf16 padded
__global__ __launch_bounds__(256) void k2_feat(
    const float* __restrict__ qkv, const float* __restrict__ cadj,
    const float* __restrict__ ivar, const float* __restrict__ ampt,
    unsigned short* __restrict__ qa_bf, unsigned short* __restrict__ kw_bf) {
  int bh = blockIdx.y; int b = bh >> 3, h = bh & 7;
  int i0 = blockIdx.x << 5;
  int tid = threadIdx.x;
  __shared__ float q_s[32][68], k_s[32][68], c_s[16][68];
#pragma unroll
  for (int t = 0; t < 4; ++t) {
    int f = tid + (t << 8);
    int mat = f >> 9, g = f & 511;
    int r = g >> 4, d4 = g & 15;
    float4 v = *(const float4*)&qkv[(size_t)(b * T_SEQ + i0 + r) * 1536 + mat * 512 + h * 64 + (d4 << 2)];
    float* dst = mat ? &k_s[r][d4 << 2] : &q_s[r][d4 << 2];
    *(float4*)dst = v;
  }
  {
    int r = tid >> 4, d4 = tid & 15;
    *(float4*)&c_s[r][d4 << 2] = *(const float4*)&cadj[(h * 16 + r) * 64 + (d4 << 2)];
  }
  __syncthreads();
#pragma unroll
  for (int t = 0; t < 4; ++t) {
    int task = (t << 8) + tid;
    int is_k = task >> 9, g = task & 511;
    int r = g >> 4, s = g & 15;
    const float* row = is_k ? k_s[r] : q_s[r];
    float acc = 0.0f;
#pragma unroll 8
    for (int d = 0; d < 64; ++d) {
      float df = row[d] - c_s[s][d];
      acc = fmaf(df, df, acc);
    }
    float val = __expf(-0.5f * acc * ivar[h * 16 + s]);
    if (!is_k) val *= ampt[h * 16 + s];
    unsigned short* dst = is_k ? kw_bf : qa_bf;
    size_t base = ((size_t)bh * T_SEQ + i0 + r) * 32;
    dst[base + s] = f2bf(val);
    dst[base + 16 + s] = 0;            // zero-pad K 16..31
  }
}

// --------------------------- K3: sinv[j] = 1/(T + sum_i expm1(l_ij))  via MFMA
__global__ __launch_bounds__(256) void k3_colsum(
    const unsigned short* __restrict__ qa_bf, const unsigned short* __restrict__ kw_bf,
    float* __restrict__ sinv) {
  int bh = blockIdx.y;
  int j0 = blockIdx.x << 6;
  int tid = threadIdx.x;
  int w = tid >> 6, l = tid & 63, lm = l & 15, lq = l >> 4;
  __shared__ __align__(16) unsigned short kws[64 * 40];
  __shared__ __align__(16) unsigned short qas[256 * 40];
  {
    int r = tid >> 2, s = tid & 3;
    *(float4*)&kws[r * 40 + s * 8] = *(const float4*)&kw_bf[((size_t)bh * T_SEQ + j0 + r) * 32 + s * 8];
  }
  __syncthreads();
  s16x8 bk = *(const s16x8*)&kws[(w * 16 + lm) * 40 + lq * 8];
  float ssum = 0.0f;
  for (int ch = 0; ch < 8; ++ch) {
    __syncthreads();
#pragma unroll
    for (int c = tid; c < 1024; c += 256) {
      int r = c >> 2, s = c & 3;
      *(float4*)&qas[r * 40 + s * 8] = *(const float4*)&qa_bf[((size_t)bh * T_SEQ + ch * 256 + r) * 32 + s * 8];
    }
    __syncthreads();
#pragma unroll 4
    for (int ii = 0; ii < 16; ++ii) {
      s16x8 aq = *(const s16x8*)&qas[(ii * 16 + lm) * 40 + lq * 8];
      f32x4 z = (f32x4){0.f, 0.f, 0.f, 0.f};
      f32x4 L = __builtin_amdgcn_mfma_f32_16x16x32_bf16(aq, bk, z, 0, 0, 0);
#pragma unroll
      for (int r = 0; r < 4; ++r) ssum += __expf(L[r]) - 1.0f;
    }
  }
  ssum += __shfl_xor(ssum, 16);
  ssum += __shfl_xor(ssum, 32);
  if (l < 16)
    sinv[(size_t)bh * T_SEQ + j0 + w * 16 + lm] = 1.0f / (2048.0f + ssum);
}

// --------------------------- K3b: vpart[js][bh][d] = sum_{j in stripe} v[j,d]*sinv[j]
__global__ __launch_bounds__(256) void k3b_vsum(
    const float* __restrict__ qkv, const float* __restrict__ sinv,
    float* __restrict__ vpart) {
  int bh = blockIdx.y; int b = bh >> 3, h = bh & 7;
  int js = blockIdx.x << 8;
  int tid = threadIdx.x;
  int d = tid & 63, jq = tid >> 6;
  __shared__ float red[4][64];
  const float* vb = qkv + (size_t)b * T_SEQ * 1536 + 1024 + h * 64 + d;
  const float* sv = sinv + (size_t)bh * T_SEQ;
  float acc = 0.0f;
#pragma unroll 4
  for (int jj = 0; jj < 64; ++jj) {
    int j = js + jq * 64 + jj;
    acc = fmaf(vb[(size_t)j * 1536], sv[j], acc);
  }
  red[jq][d] = acc;
  __syncthreads();
  if (tid < 64)
    vpart[((size_t)blockIdx.x * NBH + bh) * 64 + tid] =
        red[0][tid] + red[1][tid] + red[2][tid] + red[3][tid];
}

// ------------- K4: aout = vsum + sum_j expm1(l_ij) * v~[j,:]  (MFMA), split-bf16 out
__global__ __launch_bounds__(256) void k4_attnout(
    const unsigned short* __restrict__ qa_bf, const unsigned short* __restrict__ kw_bf,
    const float* __restrict__ sinv, const float* __restrict__ qkv,
    const float* __restrict__ vpart,
    unsigned short* __restrict__ aout_h, unsigned short* __restrict__ aout_l) {
  int bh = blockIdx.y; int b = bh >> 3, h = bh & 7;
  int i0 = blockIdx.x << 6;
  int tid = threadIdx.x;
  int w = tid >> 6, l = tid & 63, lm = l & 15, lq = l >> 4;
  __shared__ __align__(16) unsigned short qas[64 * 40];
  __shared__ __align__(16) unsigned short kws[64 * 40];
  __shared__ __align__(16) unsigned short vss[64 * 72];
  __shared__ __align__(16) unsigned short pss[64 * 72];
  {
    int r = tid >> 2, s = tid & 3;
    *(float4*)&qas[r * 40 + s * 8] = *(const float4*)&qa_bf[((size_t)bh * T_SEQ + i0 + r) * 32 + s * 8];
  }
  __syncthreads();
  s16x8 aq = *(const s16x8*)&qas[(w * 16 + lm) * 40 + lq * 8];
  f32x4 accp[4];
#pragma unroll
  for (int df = 0; df < 4; ++df) accp[df] = (f32x4){0.f, 0.f, 0.f, 0.f};

  int jj = tid & 63, dg = tid >> 6;
  const float* vbase = qkv + (size_t)b * T_SEQ * 1536 + 1024 + h * 64;
  const float* svb = sinv + (size_t)bh * T_SEQ;

  for (int jc = 0; jc < 32; ++jc) {
    int j0 = jc << 6;
    __syncthreads();
    {
      int r = tid >> 2, s = tid & 3;
      *(float4*)&kws[r * 40 + s * 8] = *(const float4*)&kw_bf[((size_t)bh * T_SEQ + j0 + r) * 32 + s * 8];
    }
    {
      float sv = svb[j0 + jj];
      const float* vp = vbase + (size_t)(j0 + jj) * 1536 + dg * 16;
#pragma unroll
      for (int q4 = 0; q4 < 4; ++q4) {
        float4 vv = *(const float4*)&vp[q4 * 4];
        vss[(dg * 16 + q4 * 4 + 0) * 72 + jj] = f2bf(vv.x * sv);
        vss[(dg * 16 + q4 * 4 + 1) * 72 + jj] = f2bf(vv.y * sv);
        vss[(dg * 16 + q4 * 4 + 2) * 72 + jj] = f2bf(vv.z * sv);
        vss[(dg * 16 + q4 * 4 + 3) * 72 + jj] = f2bf(vv.w * sv);
      }
    }
    __syncthreads();
#pragma unroll
    for (int jf = 0; jf < 4; ++jf) {
      s16x8 bk = *(const s16x8*)&kws[(jf * 16 + lm) * 40 + lq * 8];
      f32x4 z = (f32x4){0.f, 0.f, 0.f, 0.f};
      f32x4 L = __builtin_amdgcn_mfma_f32_16x16x32_bf16(aq, bk, z, 0, 0, 0);
#pragma unroll
      for (int r = 0; r < 4; ++r)
        pss[(w * 16 + lq * 4 + r) * 72 + jf * 16 + lm] = f2bf(__expf(L[r]) - 1.0f);
    }
    __syncthreads();
#pragma unroll
    for (int ks = 0; ks < 2; ++ks) {
      s16x8 ap = *(const s16x8*)&pss[(w * 16 + lm) * 72 + ks * 32 + lq * 8];
#pragma unroll
      for (int df = 0; df < 4; ++df) {
        s16x8 bv = *(const s16x8*)&vss[(df * 16 + lm) * 72 + ks * 32 + lq * 8];
        accp[df] = __builtin_amdgcn_mfma_f32_16x16x32_bf16(ap, bv, accp[df], 0, 0, 0);
      }
    }
  }
  // epilogue: add fp32 uniform term, split to bf16 hi/lo
#pragma unroll
  for (int df = 0; df < 4; ++df) {
    int d = df * 16 + lm;
    float vs = 0.0f;
#pragma unroll
    for (int js = 0; js < 8; ++js) vs += vpart[((size_t)js * NBH + bh) * 64 + d];
#pragma unroll
    for (int r = 0; r < 4; ++r) {
      int row = i0 + w * 16 + lq * 4 + r;
      float o = accp[df][r] + vs;
      unsigned short hi = f2bf(o);
      unsigned short lo = f2bf(o - bf2f(hi));
      size_t idx = ((size_t)b * T_SEQ + row) * DIMD + h * 64 + d;
      aout_h[idx] = hi;
      aout_l[idx] = lo;
    }
  }
}

// ----------------------------------------------------------------------------
extern "C" void kernel_launch(void* const* d_in, const int* in_sizes, int n_in,
                              void* d_out, int out_size, void* d_ws, size_t ws_size,
                              hipStream_t stream) {
  const float* x    = (const float*)d_in[0];
  const float* Wqkv = (const float*)d_in[1];
  const float* Wout = (const float*)d_in[2];
  const float* ctr  = (const float*)d_in[3];
  const float* dlt  = (const float*)d_in[4];
  const float* lsc  = (const float*)d_in[5];
  const float* lam  = (const float*)d_in[6];
  const float* ms   = (const float*)d_in[7];
  const float* tp   = (const float*)d_in[8];
  float* ws = (float*)d_ws;
  float* qkv   = ws + OFF_QKV;
  unsigned short* xh  = (unsigned short*)(ws + OFF_XH);
  unsigned short* xl  = (unsigned short*)(ws + OFF_XL);
  unsigned short* wqh = (unsigned short*)(ws + OFF_WQH);
  unsigned short* wql = (unsigned short*)(ws + OFF_WQL);
  unsigned short* woh = (unsigned short*)(ws + OFF_WOH);
  unsigned short* wol = (unsigned short*)(ws + OFF_WOL);
  unsigned short* qa_bf = (unsigned short*)(ws + OFF_QABF);
  unsigned short* kw_bf = (unsigned short*)(ws + OFF_KWBF);
  float* sinv  = ws + OFF_SINV;
  float* vpart = ws + OFF_VPART;
  float* cadj  = ws + OFF_CADJ;
  float* ivar  = ws + OFF_IVAR;
  float* ampt  = ws + OFF_AMPT;
  // aout aliases xh/xl (xh/xl dead after qkv GEMM)
  unsigned short* aout_h = xh;
  unsigned short* aout_l = xl;
  float* out = (float*)d_out;

  k0_params<<<1, 256, 0, stream>>>(ctr, dlt, lsc, lam, ms, tp, cadj, ivar, ampt);
  k1_split<<<2048, 256, 0, stream>>>(x, xh, xl, 524288);
  k1_split<<<768, 256, 0, stream>>>(Wqkv, wqh, wql, 196608);
  k1_split<<<256, 256, 0, stream>>>(Wout, woh, wol, 65536);
  gemm_split<128, 128><<<dim3(12, 32), 256, 0, stream>>>(xh, xl, wqh, wql, qkv, 4096, 1536, 512);
  k2_feat<<<dim3(64, 16), 256, 0, stream>>>(qkv, cadj, ivar, ampt, qa_bf, kw_bf);
  k3_colsum<<<dim3(32, 16), 256, 0, stream>>>(qa_bf, kw_bf, sinv);
  k3b_vsum<<<dim3(8, 16), 256, 0, stream>>>(qkv, sinv, vpart);
  k4_attnout<<<dim3(32, 16), 256, 0, stream>>>(qa_bf, kw_bf, sinv, qkv, vpart, aout_h, aout_l);
  gemm_split<128, 64><<<dim3(8, 32), 256, 0, stream>>>(aout_h, aout_l, woh, wol, out, 4096, 512, 512);
}